// Round 1
// baseline (294.823 us; speedup 1.0000x reference)
//
#include <hip/hip_runtime.h>

#define B_TOT 4096
#define T_LEN 512
#define DIN   8
#define H_DIM 50

typedef __attribute__((ext_vector_type(8))) short  short8;   // 8 bf16 (4 VGPRs)
typedef __attribute__((ext_vector_type(4))) float  floatx4;  // MFMA acc

__device__ __forceinline__ ushort f2bf_rne(float f) {
  uint u = __float_as_uint(f);
  u += 0x7FFFu + ((u >> 16) & 1u);
  return (ushort)(u >> 16);
}
__device__ __forceinline__ ushort f2bf_trunc(float f) {
  return (ushort)(__float_as_uint(f) >> 16);
}
__device__ __forceinline__ float bf2f(ushort b) {
  return __uint_as_float(((uint)b) << 16);
}
__device__ __forceinline__ float fast_tanh(float v) {
  // tanh(v) = 1 - 2/(1+e^{2v}); graceful at both tails, abs err ~1e-7
  float e = __expf(2.0f * v);
  return 1.0f - 2.0f * __builtin_amdgcn_rcpf(1.0f + e);
}

// LDS layout: ushort lds[4 * 1152]
//   region (q*2 + part)*1152, q = double-buffer 0/1, part 0=hi 1=lo
//   each region: A[m=0..15][k=0..71] bf16, row stride 72 elems (144 B, 16B aligned)
//   k 0..49 = h, k 50..57 = x_t, k 58..63 = zero (padded K), 64..71 = bank pad
#define ROWS 72
#define REG  1152

__global__ __launch_bounds__(256) void rnn_fused(
    const float* __restrict__ x, const float* __restrict__ W_ih,
    const float* __restrict__ W_hh, const float* __restrict__ b_ih,
    const float* __restrict__ b_hh, const float* __restrict__ fc_W,
    const float* __restrict__ fc_b, float* __restrict__ out)
{
  __shared__ __align__(16) ushort lds[4 * REG];

  const int tid  = threadIdx.x;
  const int lane = tid & 63;
  const int wave = tid >> 6;      // 0..3 -> output tile
  const int col  = lane & 15;     // MFMA n (and A-frag m)
  const int kg   = lane >> 4;     // 0..3
  const int b0   = blockIdx.x * 16;

  // ---------------- build W fragments (hi/lo split), held in VGPRs ----------
  const int iGlob = wave * 16 + col;   // output index this lane's B-column
  union U8 { ushort u[8]; short8 v; };
  U8 Bh0u, Bh1u, Bl0u, Bl1u;
#pragma unroll
  for (int hf = 0; hf < 2; ++hf) {
#pragma unroll
    for (int j = 0; j < 8; ++j) {
      int k = hf * 32 + kg * 8 + j;
      float w = 0.f;
      if (iGlob < H_DIM) {
        if (k < H_DIM)            w = W_hh[iGlob * H_DIM + k];
        else if (k < H_DIM + DIN) w = W_ih[iGlob * DIN + (k - H_DIM)];
      }
      ushort hi = f2bf_rne(w);
      ushort lo = f2bf_trunc(w - bf2f(hi));
      if (hf == 0) { Bh0u.u[j] = hi; Bl0u.u[j] = lo; }
      else         { Bh1u.u[j] = hi; Bl1u.u[j] = lo; }
    }
  }
  const short8 Bh0 = Bh0u.v, Bh1 = Bh1u.v, Bl0 = Bl0u.v, Bl1 = Bl1u.v;

  const float bv = (iGlob < H_DIM) ? (b_ih[iGlob] + b_hh[iGlob]) : 0.f;
  const floatx4 biasf = {bv, bv, bv, bv};

  // ---------------- zero LDS (h0 = 0, K-pad = 0) ----------------------------
  for (int z = tid; z < 4 * REG; z += 256) lds[z] = 0;
  __syncthreads();

  // ---------------- x staging: 128 threads, 1 fp32 each per step ------------
  const int xm = tid >> 3;   // batch row 0..15
  const int xd = tid & 7;    // d 0..7
  const float* xp = x + ((size_t)(b0 + ((tid < 128) ? xm : 0)) * T_LEN) * DIN + xd;
  float px1 = 0.f, px2 = 0.f, px3 = 0.f;
  if (tid < 128) {
    float x0 = xp[0];
    ushort xh = f2bf_rne(x0);
    lds[0 * REG + xm * ROWS + H_DIM + xd] = xh;
    lds[1 * REG + xm * ROWS + H_DIM + xd] = f2bf_trunc(x0 - bf2f(xh));
    px1 = xp[8]; px2 = xp[16]; px3 = xp[24];   // prefetch t=1,2,3
  }
  __syncthreads();

  // ---------------- main recurrence ----------------------------------------
  // step t: reads buf p = t&1 (holds h_t, x_t), writes h_{t+1}, x_{t+1} to q
  auto step = [&](int t, int offph, int offpl, int offqh, int offql) {
    const int rb = col * ROWS + kg * 8;
    short8 Ah0 = *(const short8*)(lds + offph + rb);
    short8 Ah1 = *(const short8*)(lds + offph + rb + 32);
    short8 Al0 = *(const short8*)(lds + offpl + rb);
    short8 Al1 = *(const short8*)(lds + offpl + rb + 32);

    floatx4 acc = biasf;
    acc = __builtin_amdgcn_mfma_f32_16x16x32_bf16(Ah0, Bh0, acc, 0, 0, 0);
    acc = __builtin_amdgcn_mfma_f32_16x16x32_bf16(Ah1, Bh1, acc, 0, 0, 0);
    acc = __builtin_amdgcn_mfma_f32_16x16x32_bf16(Al0, Bh0, acc, 0, 0, 0);
    acc = __builtin_amdgcn_mfma_f32_16x16x32_bf16(Al1, Bh1, acc, 0, 0, 0);
    floatx4 accB = {0.f, 0.f, 0.f, 0.f};
    accB = __builtin_amdgcn_mfma_f32_16x16x32_bf16(Ah0, Bl0, accB, 0, 0, 0);
    accB = __builtin_amdgcn_mfma_f32_16x16x32_bf16(Ah1, Bl1, accB, 0, 0, 0);

    // epilogue: tanh, hi/lo split, write h_{t+1} (C layout: m=kg*4+r, n=col)
    if (iGlob < H_DIM) {
#pragma unroll
      for (int r = 0; r < 4; ++r) {
        float v  = acc[r] + accB[r];
        float th = fast_tanh(v);
        ushort hi = f2bf_rne(th);
        ushort lo = f2bf_trunc(th - bf2f(hi));
        int m = kg * 4 + r;
        lds[offqh + m * ROWS + iGlob] = hi;
        lds[offql + m * ROWS + iGlob] = lo;
      }
    }
    // stage x_{t+1} into q; rotate depth-3 prefetch pipeline
    if (tid < 128) {
      ushort xh = f2bf_rne(px1);
      ushort xl = f2bf_trunc(px1 - bf2f(xh));
      lds[offqh + xm * ROWS + H_DIM + xd] = xh;
      lds[offql + xm * ROWS + H_DIM + xd] = xl;
      px1 = px2; px2 = px3;
      int tn = t + 4; if (tn > T_LEN - 1) tn = T_LEN - 1;
      px3 = xp[tn * 8];
    }
    __syncthreads();
  };

  for (int t = 0; t < T_LEN; t += 2) {
    step(t,     0 * REG, 1 * REG, 2 * REG, 3 * REG);  // buf0 -> buf1
    step(t + 1, 2 * REG, 3 * REG, 0 * REG, 1 * REG);  // buf1 -> buf0
  }
  // h_512 now in buf0 (hi at 0, lo at REG)

  // ---------------- fc readout: wave 0, 4 lanes per batch -------------------
  if (tid < 64) {
    int m = tid >> 2, kq = tid & 3;
    float acc2 = 0.f;
    for (int k = kq; k < H_DIM; k += 4) {
      float hv = bf2f(lds[0 * REG + m * ROWS + k]) + bf2f(lds[1 * REG + m * ROWS + k]);
      acc2 += hv * fc_W[k];
    }
    acc2 += __shfl_xor(acc2, 1);
    acc2 += __shfl_xor(acc2, 2);
    if (kq == 0) out[b0 + m] = acc2 + fc_b[0];
  }
}

extern "C" void kernel_launch(void* const* d_in, const int* in_sizes, int n_in,
                              void* d_out, int out_size, void* d_ws, size_t ws_size,
                              hipStream_t stream) {
  const float* x    = (const float*)d_in[0];
  const float* W_ih = (const float*)d_in[1];
  const float* W_hh = (const float*)d_in[2];
  const float* b_ih = (const float*)d_in[3];
  const float* b_hh = (const float*)d_in[4];
  const float* fc_W = (const float*)d_in[5];
  const float* fc_b = (const float*)d_in[6];
  rnn_fused<<<dim3(B_TOT / 16), dim3(256), 0, stream>>>(
      x, W_ih, W_hh, b_ih, b_hh, fc_W, fc_b, (float*)d_out);
}